// Round 9
// baseline (148.546 us; speedup 1.0000x reference)
//
#include <hip/hip_runtime.h>
#include <math.h>

// FM model: out[s] = sigmoid(0.5*sum_e((sum_f v)^2 - sum_f v^2) + sum_f linear)
// user[16384,20,33], ctx[16384,10,33], doc[16384,30,33]
//
// R6 post-mortem: compiler sank the register-staged loads to the LDS-store
// site (VGPR=44 proves no live 36-VGPR buffer) -> same serial
// stage->drain->compute as R4/R5, all ~43us. Source-level reg pipelining is
// compiler-defeated.
// R7: global_load_lds double-buffer + counted vmcnt + RAW s_barrier
// (NOT __syncthreads, which emits vmcnt(0) and drains the prefetch).
// Wave 0 stages user+ctx (495 f4), wave 1 doc (495 f4): 8 glds/wave/STAGE,
// so vmcnt(8) waits exactly for the current buffer while next-pair loads
// stay in flight. 1024 blocks x 8 pairs, 31.7KB LDS, 4 blocks/CU resident.

#define NS 16384
#define PPB 8  // pairs per block; 8192 pairs / 1024 blocks

__device__ __forceinline__ void glds16(const void* g, void* l) {
  __builtin_amdgcn_global_load_lds(
      (const __attribute__((address_space(1))) void*)g,
      (__attribute__((address_space(3))) void*)l,
      16, 0, 0);
}

__global__ __launch_bounds__(128) void fm_kernel(
    const float* __restrict__ user,
    const float* __restrict__ ctx,
    const float* __restrict__ doc,
    float* __restrict__ out) {
  // two pair-buffers: [user 1320 | ctx 660 | doc 1980] floats each = 15,840B
  __shared__ float smem[2 * 3960];

  const int tid  = threadIdx.x;
  const int w    = tid >> 6;   // wave id (0..1)
  const int lane = tid & 63;
  const int pair0 = blockIdx.x * PPB;

  // STAGE: issue exactly 8 global_load_lds dwordx4 per wave.
  // LDS dest must be wave-uniform (HW adds lane*16); global src is per-lane.
  auto STAGE = [&](int cb, int pair) {
    float* buf = smem + cb * 3960;
    if (w == 0) {
      // flat k over [0,495): user-pair 330 f4 then ctx-pair 165 f4
      const float4* gu = (const float4*)(user + (size_t)(2 * pair) * 660);
      const float4* gc = (const float4*)(ctx  + (size_t)(2 * pair) * 330);
#pragma unroll
      for (int i = 0; i < 8; ++i) {
        int k = i * 64 + lane;
        const float4* src = (k < 330) ? (gu + k) : (gc + (k - 330));
        if (k < 495) glds16(src, buf + i * 256);  // uniform dst: i*64 f4
      }
    } else {
      // doc-pair: 495 f4 into region starting at float 1980
      const float4* gd = (const float4*)(doc + (size_t)(2 * pair) * 990);
      float* dbase = buf + 1980;
#pragma unroll
      for (int i = 0; i < 8; ++i) {
        int k = i * 64 + lane;
        if (k < 495) glds16(gd + k, dbase + i * 256);
      }
    }
  };

  // compute-lane mapping: wave w owns sample 2*pair+w
  const int h = (lane >> 5);   // field-half (0: user+ctx, 1: doc)
  const int e = lane & 31;     // latent element

  STAGE(0, pair0);  // prologue: 8 outstanding per wave

  for (int it = 0; it < PPB; ++it) {
    const int cur = it & 1;
    const bool more = (it + 1 < PPB);
    if (more) STAGE(cur ^ 1, pair0 + it + 1);  // +8 -> 16 outstanding

    // wait ONLY for current buffer's 8; next-pair 8 stay in flight
    if (more) asm volatile("s_waitcnt vmcnt(8)" ::: "memory");
    else      asm volatile("s_waitcnt vmcnt(0)" ::: "memory");
    __builtin_amdgcn_s_barrier();  // publish cross-wave (raw: no auto-drain)

    const float* base = smem + cur * 3960;
    const float* mu = base + w * 660;
    const float* mc = base + 1320 + w * 330;
    const float* md = base + 1980 + w * 990;
    const float* p1 = (h ? md : mu) + e;
    const float* p2 = (h ? (md + 660) : mc) + e;

    float sv = 0.f, sv2 = 0.f;
#pragma unroll
    for (int f = 0; f < 20; ++f) {
      float x = p1[f * 33];
      sv += x; sv2 = fmaf(x, x, sv2);
    }
#pragma unroll
    for (int f = 0; f < 10; ++f) {
      float x = p2[f * 33];
      sv += x; sv2 = fmaf(x, x, sv2);
    }

    float lin = 0.f;
    if (h == 0) {
      if (e < 20)      lin = mu[e * 33 + 32];
      else if (e < 30) lin = mc[(e - 20) * 33 + 32];
    } else {
      if (e < 30) lin = md[e * 33 + 32];
    }

    // merge field-halves, then reduce over the 32 elements
    float svT  = sv  + __shfl_xor(sv,  32, 64);
    float sv2T = sv2 + __shfl_xor(sv2, 32, 64);
    float linT = lin + __shfl_xor(lin, 32, 64);
    float part = fmaf(svT, svT, -sv2T);
#pragma unroll
    for (int m = 16; m > 0; m >>= 1) {
      part += __shfl_xor(part, m, 64);
      linT += __shfl_xor(linT, m, 64);
    }
    if (lane == 0) {
      float logit = fmaf(0.5f, part, linT);
      out[2 * (pair0 + it) + w] = 1.f / (1.f + expf(-logit));
    }

    // all waves done reading buf[cur] before next iter's STAGE overwrites it
    __builtin_amdgcn_s_barrier();
  }
}

extern "C" void kernel_launch(void* const* d_in, const int* in_sizes, int n_in,
                              void* d_out, int out_size, void* d_ws, size_t ws_size,
                              hipStream_t stream) {
  const float* user = (const float*)d_in[0];
  const float* ctx  = (const float*)d_in[1];
  const float* doc  = (const float*)d_in[2];
  float* out = (float*)d_out;

  // 1024 resident blocks (4/CU by LDS) x 8 pairs = 8192 pairs = 16384 samples
  dim3 block(128);
  dim3 grid(NS / 2 / PPB);
  fm_kernel<<<grid, block, 0, stream>>>(user, ctx, doc, out);
}

// Round 13
// 142.649 us; speedup vs baseline: 1.0413x; 1.0413x over previous
//
#include <hip/hip_runtime.h>
#include <math.h>

// FM model: out[s] = sigmoid(0.5*sum_e((sum_f v)^2 - sum_f v^2) + sum_f linear)
// user[16384,20,33], ctx[16384,10,33], doc[16384,30,33]
//
// R7 post-mortem: four different LDS-staged structures all saturate at
// ~3.1 TB/s effective (42-44us); counted-vmcnt pipeline didn't bind on
// latency but on supply through the staging path. R9: NO LDS — direct
// wide loads to registers. gfx950 global_load_dwordx4 needs only dword
// alignment, so the 33-float row stride is loadable as align(4) float4.
// 8 lanes/row: lane k owns elements [4k,4k+4) of every row -> S_e
// accumulates in 4 regs, no data movement until the final butterfly.
// Wave-per-sample, 8 rounds x 8 rows, no barriers, no LDS.

#define NS 16384

typedef float f4u __attribute__((ext_vector_type(4), aligned(4)));

__global__ __launch_bounds__(256, 4) void fm_kernel(
    const float* __restrict__ user,
    const float* __restrict__ ctx,
    const float* __restrict__ doc,
    float* __restrict__ out) {
  const int tid = threadIdx.x;
  const int w   = tid >> 6;          // wave in block
  const int l   = tid & 63;          // lane
  const int s   = blockIdx.x * 4 + w;

  const int k  = l & 7;              // position in row: elements [4k, 4k+4)
  const int rg = l >> 3;             // row group (0..7)

  const float* __restrict__ ub = user + (size_t)s * 660;
  const float* __restrict__ cb = ctx  + (size_t)s * 330;
  const float* __restrict__ db = doc  + (size_t)s * 990;

  // row r (0..59) -> pointer to row start (33-float stride per array)
  auto rowptr = [&](int r) -> const float* {
    return r < 20 ? ub + r * 33
         : (r < 30 ? cb + (r - 20) * 33
                   : db + (r - 30) * 33);
  };

  // linear terms: lane l<60 loads row l's col 32
  float lin = 0.f;
  if (l < 60) lin = rowptr(l)[32];

  float4 S = {0.f, 0.f, 0.f, 0.f};
  float q = 0.f;

#pragma unroll
  for (int j = 0; j < 8; ++j) {
    const int r = 8 * j + rg;         // row for this lane this round
    if (j < 7 || rg < 4) {            // round 7: only rows 56..59
      const f4u x = *(const f4u*)(rowptr(r) + 4 * k);  // align-4 dwordx4
      S.x += x[0]; S.y += x[1]; S.z += x[2]; S.w += x[3];
      q = fmaf(x[0], x[0], fmaf(x[1], x[1],
          fmaf(x[2], x[2], fmaf(x[3], x[3], q))));
    }
  }

  // phase 1: reduce over the 8 row-groups (masks 8,16,32).
  // After this, all lanes in a k-class hold S_e complete for e in [4k,4k+4),
  // q summed over those e (all rows), lin partially reduced.
#pragma unroll
  for (int m = 8; m <= 32; m <<= 1) {
    S.x += __shfl_xor(S.x, m, 64);
    S.y += __shfl_xor(S.y, m, 64);
    S.z += __shfl_xor(S.z, m, 64);
    S.w += __shfl_xor(S.w, m, 64);
    q   += __shfl_xor(q,   m, 64);
    lin += __shfl_xor(lin, m, 64);
  }

  // per-k-class cross term: sum_{e in class} S_e^2 - Q_e
  float pp = S.x * S.x + S.y * S.y + S.z * S.z + S.w * S.w - q;

  // phase 2: sum the 8 k-classes (masks 1,2,4); completes lin's butterfly too
#pragma unroll
  for (int m = 1; m <= 4; m <<= 1) {
    pp  += __shfl_xor(pp,  m, 64);
    lin += __shfl_xor(lin, m, 64);
  }

  if (l == 0) {
    float logit = fmaf(0.5f, pp, lin);
    out[s] = 1.f / (1.f + expf(-logit));
  }
}

extern "C" void kernel_launch(void* const* d_in, const int* in_sizes, int n_in,
                              void* d_out, int out_size, void* d_ws, size_t ws_size,
                              hipStream_t stream) {
  const float* user = (const float*)d_in[0];
  const float* ctx  = (const float*)d_in[1];
  const float* doc  = (const float*)d_in[2];
  float* out = (float*)d_out;

  // wave-per-sample: 256 threads = 4 samples/block, 4096 blocks
  dim3 block(256);
  dim3 grid(NS / 4);
  fm_kernel<<<grid, block, 0, stream>>>(user, ctx, doc, out);
}